// Round 1
// 949.073 us; speedup vs baseline: 1.4237x; 1.4237x over previous
//
#include <hip/hip_runtime.h>
#include <math.h>

#define B_    4
#define T_    2048
#define D_    1024
#define DB_   256
#define DKk_  128
#define KV_   48
#define DIN_  1408
#define NT_   (B_ * T_)      // 8192 tokens
#define RAD_  8

// ---------------------------------------------------------------------------
// workspace layout
//   f32 region (float offsets):
#define OFS_BOUND  0                      // 8192
#define OFS_BSOFT  8192                   // 8192
#define OFS_KEY    16384                  // 8192*48
#define OFS_EK     409600                 // 8192*128
#define OFS_HSTAT  1458176                // 8192*2 (mean_h, rstd_h)
#define OFS_BF16   1474560                // start of bf16 region (floats)
//   bf16 region (ushort offsets from ws + OFS_BF16):
#define UOFS_AHI   0u                     // 8192*1408
#define UOFS_ALO   11534336u              // 8192*1408
#define UOFS_BHI   23068672u              // 2048*1408  (W^T, hi)
#define UOFS_BLO   25952256u              // 2048*1408  (W^T, lo)
// total = 5,898,240 + 57,671,680 bytes = 63.6 MB

typedef __attribute__((ext_vector_type(8))) short s16x8;
typedef __attribute__((ext_vector_type(4))) float f32x4;

__device__ __forceinline__ unsigned short f2bf(float f) {
    unsigned u; __builtin_memcpy(&u, &f, 4);
    u += 0x7fffu + ((u >> 16) & 1u);
    return (unsigned short)(u >> 16);
}
__device__ __forceinline__ unsigned short f2bf_hi(float f, float* back) {
    unsigned u; __builtin_memcpy(&u, &f, 4);
    u += 0x7fffu + ((u >> 16) & 1u);
    unsigned short h = (unsigned short)(u >> 16);
    unsigned hb = (unsigned)h << 16;
    __builtin_memcpy(back, &hb, 4);
    return h;
}
__device__ __forceinline__ void gload_lds16(const void* g, void* s) {
    __builtin_amdgcn_global_load_lds(
        (const __attribute__((address_space(1))) unsigned int*)g,
        (__attribute__((address_space(3))) unsigned int*)s,
        16, 0, 0);
}

// ---------------------------------------------------------------------------
// K0: transpose+split film_w (f32 [1408][2048]) -> B_hi/B_lo bf16 [2048][1408]
// ---------------------------------------------------------------------------
__global__ __launch_bounds__(256) void k_prepw(
    const float* __restrict__ film_w, unsigned short* __restrict__ Bhi,
    unsigned short* __restrict__ Blo)
{
    __shared__ float tile[32][33];
    const int n0 = blockIdx.x * 32;     // 0..2047
    const int k0 = blockIdx.y * 32;     // 0..1407
    const int tid = threadIdx.x;
    const int c = tid & 31, r0 = tid >> 5;
    #pragma unroll
    for (int i = 0; i < 4; ++i) {
        int r = r0 + i * 8;
        tile[r][c] = film_w[(size_t)(k0 + r) * 2048 + n0 + c];
    }
    __syncthreads();
    #pragma unroll
    for (int i = 0; i < 4; ++i) {
        int rn = r0 + i * 8;            // n within tile
        float f = tile[c][rn];          // film_w[k0+c][n0+rn]
        float fh;
        unsigned short hs = f2bf_hi(f, &fh);
        unsigned short ls = f2bf(f - fh);
        Bhi[(size_t)(n0 + rn) * 1408 + k0 + c] = hs;
        Blo[(size_t)(n0 + rn) * 1408 + k0 + c] = ls;
    }
}

// ---------------------------------------------------------------------------
// K1: boundary logit + key logits (49-col mini-GEMM, 32 tokens / block)
// ---------------------------------------------------------------------------
__global__ __launch_bounds__(256) void k_logits(
    const float* __restrict__ h, const float* __restrict__ bound_w,
    const float* __restrict__ bound_b, const float* __restrict__ key_w,
    const float* __restrict__ key_b, float* __restrict__ ws)
{
    __shared__ float As[32][64];
    __shared__ float Ws[64][64];
    const int tid  = threadIdx.x;
    const int tok0 = blockIdx.x * 32;
    const int c  = tid & 63;
    const int rg = tid >> 6;
    float acc[8] = {0,0,0,0,0,0,0,0};

    for (int kc = 0; kc < 1024; kc += 64) {
        #pragma unroll
        for (int i = 0; i < 8; ++i) {
            int row = rg + 4 * i;
            As[row][c] = h[(size_t)(tok0 + row) * 1024 + kc + c];
        }
        #pragma unroll
        for (int i = 0; i < 12; ++i) {
            int l = tid + 256 * i;
            int r = l / 48, cc = l - r * 48;
            Ws[r][cc] = key_w[(size_t)(kc + r) * 48 + cc];
        }
        if (tid < 64) Ws[tid][48] = bound_w[kc + tid];
        __syncthreads();
        #pragma unroll 8
        for (int kk = 0; kk < 64; ++kk) {
            float w = Ws[kk][c];
            #pragma unroll
            for (int i = 0; i < 8; ++i)
                acc[i] += As[rg * 8 + i][kk] * w;
        }
        __syncthreads();
    }

    if (c < 48) {
        float kb = key_b[c];
        #pragma unroll
        for (int i = 0; i < 8; ++i)
            ws[OFS_KEY + (size_t)(tok0 + rg * 8 + i) * 48 + c] = acc[i] + kb;
    } else if (c == 48) {
        float bb = bound_b[0];
        #pragma unroll
        for (int i = 0; i < 8; ++i)
            ws[OFS_BOUND + tok0 + rg * 8 + i] = acc[i] + bb;
    }
}

// ---------------------------------------------------------------------------
// K2: 9-tap conv (zero pad) + sigmoid -> b_soft
// ---------------------------------------------------------------------------
__global__ __launch_bounds__(256) void k_conv(
    const float* __restrict__ conv_w, const float* __restrict__ conv_b,
    float* __restrict__ ws)
{
    int id = blockIdx.x * 256 + threadIdx.x;
    if (id >= NT_) return;
    int b = id >> 11, t = id & 2047;
    float s = conv_b[0];
    #pragma unroll
    for (int i = 0; i < 9; ++i) {
        int tt = t + i - 4;
        if (tt >= 0 && tt < T_) s += ws[OFS_BOUND + b * T_ + tt] * conv_w[i];
    }
    ws[OFS_BSOFT + id] = 1.0f / (1.0f + expf(-s));
}

// ---------------------------------------------------------------------------
// K3: softmax over 48 keys, then p @ key_emb -> ek (128)
// ---------------------------------------------------------------------------
__global__ __launch_bounds__(128) void k_softek(
    const float* __restrict__ key_emb, float* __restrict__ ws)
{
    __shared__ float p[48];
    const int tok = blockIdx.x;
    const int tid = threadIdx.x;
    if (tid < 64) {
        float v = (tid < 48) ? ws[OFS_KEY + (size_t)tok * 48 + tid] : -1e30f;
        float m = v;
        #pragma unroll
        for (int off = 32; off; off >>= 1) m = fmaxf(m, __shfl_xor(m, off, 64));
        float e = (tid < 48) ? expf(v - m) : 0.0f;
        float s = e;
        #pragma unroll
        for (int off = 32; off; off >>= 1) s += __shfl_xor(s, off, 64);
        if (tid < 48) p[tid] = e / s;
    }
    __syncthreads();
    float acc = 0.0f;
    #pragma unroll 8
    for (int k = 0; k < 48; ++k) acc += p[k] * key_emb[k * 128 + tid];
    ws[OFS_EK + (size_t)tok * 128 + tid] = acc;
}

// ---------------------------------------------------------------------------
// K4: film_in = LN([h, eb, ek]) -> split bf16 (A_hi, A_lo); h-row LN stats
// ---------------------------------------------------------------------------
__global__ __launch_bounds__(256) void k_filmin(
    const float* __restrict__ h, const float* __restrict__ e0,
    const float* __restrict__ e1, const float* __restrict__ ln_in_g,
    const float* __restrict__ ln_in_b, float* __restrict__ ws,
    unsigned short* __restrict__ Ahi, unsigned short* __restrict__ Alo)
{
    const int tok = blockIdx.x;
    const int tid = threadIdx.x;
    const float bs = ws[OFS_BSOFT + tok];
    float val[6];
    float s_all = 0.f, ss_all = 0.f, s_h = 0.f, ss_h = 0.f;
    int n = 0;
    for (int j = tid; j < DIN_; j += 256, ++n) {
        float v;
        if (j < 1024)       v = h[(size_t)tok * 1024 + j];
        else if (j < 1280)  { int i = j - 1024; v = bs * e1[i] + (1.0f - bs) * e0[i]; }
        else                v = ws[OFS_EK + (size_t)tok * 128 + (j - 1280)];
        val[n] = v;
        s_all += v; ss_all += v * v;
        if (j < 1024) { s_h += v; ss_h += v * v; }
    }
    #pragma unroll
    for (int off = 32; off; off >>= 1) {
        s_all  += __shfl_down(s_all, off);
        ss_all += __shfl_down(ss_all, off);
        s_h    += __shfl_down(s_h, off);
        ss_h   += __shfl_down(ss_h, off);
    }
    __shared__ float red[4][4];
    const int wid = tid >> 6;
    if ((tid & 63) == 0) {
        red[wid][0] = s_all; red[wid][1] = ss_all;
        red[wid][2] = s_h;   red[wid][3] = ss_h;
    }
    __syncthreads();
    float S   = red[0][0] + red[1][0] + red[2][0] + red[3][0];
    float SS  = red[0][1] + red[1][1] + red[2][1] + red[3][1];
    float Sh  = red[0][2] + red[1][2] + red[2][2] + red[3][2];
    float SSh = red[0][3] + red[1][3] + red[2][3] + red[3][3];
    float mean  = S * (1.0f / 1408.0f);
    float var   = SS * (1.0f / 1408.0f) - mean * mean;
    float rstd  = rsqrtf(var + 1e-5f);
    float mean_h = Sh * (1.0f / 1024.0f);
    float var_h  = SSh * (1.0f / 1024.0f) - mean_h * mean_h;
    float rstd_h = rsqrtf(var_h + 1e-5f);
    if (tid == 0) {
        ws[OFS_HSTAT + tok * 2]     = mean_h;
        ws[OFS_HSTAT + tok * 2 + 1] = rstd_h;
    }
    n = 0;
    for (int j = tid; j < DIN_; j += 256, ++n) {
        float f = (val[n] - mean) * rstd * ln_in_g[j] + ln_in_b[j];
        float fh;
        unsigned short hs = f2bf_hi(f, &fh);
        Ahi[(size_t)tok * 1408 + j] = hs;
        Alo[(size_t)tok * 1408 + j] = f2bf(f - fh);
    }
}

// ---------------------------------------------------------------------------
// K5: split-bf16 MFMA GEMM. 3 sections (Ahi*Bhi + Alo*Bhi + Ahi*Blo), fp32
//     accumulate. Tile: 128 tokens x 64 cols, DUAL gamma/beta strips.
//     global_load_lds(16B) staging, inverse-swizzled source + XOR-swizzled
//     ds_read_b128 (breaks the 128B-row 32-way bank conflict).
//     Fused epilogue: z = LN(h)*(1+gamma)+beta -> out slot 0.
// ---------------------------------------------------------------------------
__global__ __launch_bounds__(256) void k_gemm_mfma(
    const unsigned short* __restrict__ Ahi, const unsigned short* __restrict__ Alo,
    const unsigned short* __restrict__ Bhi, const unsigned short* __restrict__ Blo,
    const float* __restrict__ film_b, const float* __restrict__ h,
    const float* __restrict__ hstat, const float* __restrict__ ln_h_g,
    const float* __restrict__ ln_h_b, float* __restrict__ out)
{
    // LDS: A tile [128][64] bf16 @0 (16KB), Bg [64][64] @16384, Bb @24576
    __shared__ __align__(16) char lds[32768];
    const int tid  = threadIdx.x;
    const int m0   = blockIdx.x * 128;
    const int n0   = blockIdx.y * 64;
    const int lane = tid & 63;
    const int wid  = tid >> 6;
    const int wm   = wid >> 1, wn = wid & 1;      // wave grid 2x2
    const int lr   = lane & 15;
    const int hi16 = ((lane >> 4) & 3) * 16;      // byte offset of 8-elem k-chunk
    const int sa   = (lr & 7) << 4;               // read-side XOR swizzle
    // staging: thread t stages 16B; LDS linear dest, source k pre-swizzled
    const int srow = tid >> 3;                    // 0..31 (+c*32)
    const int sswz = ((((tid & 7) * 16) ^ ((srow & 7) << 4)) >> 1); // ushort off
    const int sdst = tid * 16;

    f32x4 accg[4][2] = {};
    f32x4 accb[4][2] = {};

    #pragma unroll
    for (int s = 0; s < 3; ++s) {
        const unsigned short* Ap = (s == 1) ? Alo : Ahi;
        const unsigned short* Bp = (s == 2) ? Blo : Bhi;
        for (int kc = 0; kc < 1408; kc += 64) {
            #pragma unroll
            for (int c = 0; c < 4; ++c)
                gload_lds16(Ap + (size_t)(m0 + srow + c * 32) * 1408 + kc + sswz,
                            lds + c * 4096 + sdst);
            #pragma unroll
            for (int c = 0; c < 2; ++c) {
                gload_lds16(Bp + (size_t)(n0 + srow + c * 32) * 1408 + kc + sswz,
                            lds + 16384 + c * 4096 + sdst);
                gload_lds16(Bp + (size_t)(1024 + n0 + srow + c * 32) * 1408 + kc + sswz,
                            lds + 24576 + c * 4096 + sdst);
            }
            __syncthreads();   // compiler drains vmcnt(0) here
            #pragma unroll
            for (int ks = 0; ks < 2; ++ks) {
                s16x8 af[4], bg[2], bb[2];
                #pragma unroll
                for (int mt = 0; mt < 4; ++mt) {
                    int row = wm * 64 + mt * 16 + lr;
                    af[mt] = *(const s16x8*)(lds + row * 128 + ((ks * 64 + hi16) ^ sa));
                }
                #pragma unroll
                for (int nt = 0; nt < 2; ++nt) {
                    int off = (wn * 32 + nt * 16 + lr) * 128 + ((ks * 64 + hi16) ^ sa);
                    bg[nt] = *(const s16x8*)(lds + 16384 + off);
                    bb[nt] = *(const s16x8*)(lds + 24576 + off);
                }
                #pragma unroll
                for (int mt = 0; mt < 4; ++mt)
                    #pragma unroll
                    for (int nt = 0; nt < 2; ++nt) {
                        accg[mt][nt] = __builtin_amdgcn_mfma_f32_16x16x32_bf16(
                            af[mt], bg[nt], accg[mt][nt], 0, 0, 0);
                        accb[mt][nt] = __builtin_amdgcn_mfma_f32_16x16x32_bf16(
                            af[mt], bb[nt], accb[mt][nt], 0, 0, 0);
                    }
            }
            __syncthreads();
        }
    }

    // epilogue: C/D layout col=lane&15, row=(lane>>4)*4+reg
    #pragma unroll
    for (int mt = 0; mt < 4; ++mt) {
        #pragma unroll
        for (int r = 0; r < 4; ++r) {
            const int tok = m0 + wm * 64 + mt * 16 + ((lane >> 4) & 3) * 4 + r;
            const float mh = hstat[tok * 2], rh = hstat[tok * 2 + 1];
            #pragma unroll
            for (int nt = 0; nt < 2; ++nt) {
                const int nc = n0 + wn * 32 + nt * 16 + lr;
                float g  = accg[mt][nt][r] + film_b[nc];
                float bt = accb[mt][nt][r] + film_b[1024 + nc];
                float hv = h[(size_t)tok * 1024 + nc];
                float lnh = (hv - mh) * rh * ln_h_g[nc] + ln_h_b[nc];
                out[(size_t)tok * (18 * 1024) + nc] = lnh * (1.0f + g) + bt;
            }
        }
    }
}

// ---------------------------------------------------------------------------
// K6: window copy, slots 1..17. One block per token, 17 float4 per thread.
// ---------------------------------------------------------------------------
__global__ __launch_bounds__(256) void k_window(
    const float* __restrict__ h, float* __restrict__ out)
{
    const int tokg = blockIdx.x;
    const int t = tokg & 2047, b = tokg >> 11;
    float4* dst = (float4*)&out[(size_t)tokg * 18 * 1024];
    #pragma unroll 4
    for (int slot = 0; slot < 17; ++slot) {
        int st = t + slot - RAD_;
        st = st < 0 ? 0 : (st > T_ - 1 ? T_ - 1 : st);
        const float4* src = (const float4*)&h[(size_t)(b * T_ + st) * 1024];
        dst[(1 + slot) * 256 + threadIdx.x] = src[threadIdx.x];
    }
}

// ---------------------------------------------------------------------------
extern "C" void kernel_launch(void* const* d_in, const int* in_sizes, int n_in,
                              void* d_out, int out_size, void* d_ws, size_t ws_size,
                              hipStream_t stream)
{
    const float* h       = (const float*)d_in[0];
    const float* bound_w = (const float*)d_in[1];
    const float* bound_b = (const float*)d_in[2];
    const float* conv_w  = (const float*)d_in[3];
    const float* conv_b  = (const float*)d_in[4];
    const float* e0      = (const float*)d_in[5];
    const float* e1      = (const float*)d_in[6];
    const float* key_emb = (const float*)d_in[7];
    const float* key_w   = (const float*)d_in[8];
    const float* key_b   = (const float*)d_in[9];
    const float* ln_in_g = (const float*)d_in[10];
    const float* ln_in_b = (const float*)d_in[11];
    const float* film_w  = (const float*)d_in[12];
    const float* film_b  = (const float*)d_in[13];
    const float* ln_h_g  = (const float*)d_in[14];
    const float* ln_h_b  = (const float*)d_in[15];
    float* ws  = (float*)d_ws;
    float* out = (float*)d_out;
    unsigned short* ub  = (unsigned short*)(ws + OFS_BF16);
    unsigned short* Ahi = ub + UOFS_AHI;
    unsigned short* Alo = ub + UOFS_ALO;
    unsigned short* Bhi = ub + UOFS_BHI;
    unsigned short* Blo = ub + UOFS_BLO;

    hipLaunchKernelGGL(k_prepw, dim3(64, 44), dim3(256), 0, stream,
                       film_w, Bhi, Blo);
    hipLaunchKernelGGL(k_logits, dim3(NT_ / 32), dim3(256), 0, stream,
                       h, bound_w, bound_b, key_w, key_b, ws);
    hipLaunchKernelGGL(k_conv, dim3(NT_ / 256), dim3(256), 0, stream,
                       conv_w, conv_b, ws);
    hipLaunchKernelGGL(k_softek, dim3(NT_), dim3(128), 0, stream, key_emb, ws);
    hipLaunchKernelGGL(k_filmin, dim3(NT_), dim3(256), 0, stream,
                       h, e0, e1, ln_in_g, ln_in_b, ws, Ahi, Alo);
    hipLaunchKernelGGL(k_gemm_mfma, dim3(64, 16), dim3(256), 0, stream,
                       Ahi, Alo, Bhi, Blo, film_b, h, ws + OFS_HSTAT,
                       ln_h_g, ln_h_b, out);
    hipLaunchKernelGGL(k_window, dim3(NT_), dim3(256), 0, stream, h, out);
}

// Round 2
// 909.744 us; speedup vs baseline: 1.4853x; 1.0432x over previous
//
#include <hip/hip_runtime.h>
#include <math.h>

#define B_    4
#define T_    2048
#define D_    1024
#define DB_   256
#define DKk_  128
#define KV_   48
#define DIN_  1408
#define NT_   (B_ * T_)      // 8192 tokens
#define RAD_  8

// ---------------------------------------------------------------------------
// workspace layout
//   f32 region (float offsets):
#define OFS_BOUND  0                      // 8192
#define OFS_BSOFT  8192                   // 8192
#define OFS_KEY    16384                  // 8192*48
#define OFS_EK     409600                 // 8192*128
#define OFS_HSTAT  1458176                // 8192*2 (mean_h, rstd_h)
#define OFS_BF16   1474560                // start of bf16 region (floats)
//   bf16 region (ushort offsets from ws + OFS_BF16):
#define UOFS_AHI   0u                     // 8192*1408
#define UOFS_ALO   11534336u              // 8192*1408
#define UOFS_BHI   23068672u              // 2048*1408  (W^T, hi)
#define UOFS_BLO   25952256u              // 2048*1408  (W^T, lo)
// total = 5,898,240 + 57,671,680 bytes = 63.6 MB

typedef __attribute__((ext_vector_type(8))) short s16x8;
typedef __attribute__((ext_vector_type(4))) float f32x4;

__device__ __forceinline__ unsigned short f2bf(float f) {
    unsigned u; __builtin_memcpy(&u, &f, 4);
    u += 0x7fffu + ((u >> 16) & 1u);
    return (unsigned short)(u >> 16);
}
__device__ __forceinline__ unsigned short f2bf_hi(float f, float* back) {
    unsigned u; __builtin_memcpy(&u, &f, 4);
    u += 0x7fffu + ((u >> 16) & 1u);
    unsigned short h = (unsigned short)(u >> 16);
    unsigned hb = (unsigned)h << 16;
    __builtin_memcpy(back, &hb, 4);
    return h;
}
__device__ __forceinline__ void gload_lds16(const void* g, void* s) {
    __builtin_amdgcn_global_load_lds(
        (const __attribute__((address_space(1))) unsigned int*)g,
        (__attribute__((address_space(3))) unsigned int*)s,
        16, 0, 0);
}

// ---------------------------------------------------------------------------
// K0: transpose+split film_w (f32 [1408][2048]) -> B_hi/B_lo bf16 [2048][1408]
// ---------------------------------------------------------------------------
__global__ __launch_bounds__(256) void k_prepw(
    const float* __restrict__ film_w, unsigned short* __restrict__ Bhi,
    unsigned short* __restrict__ Blo)
{
    __shared__ float tile[32][33];
    const int n0 = blockIdx.x * 32;     // 0..2047
    const int k0 = blockIdx.y * 32;     // 0..1407
    const int tid = threadIdx.x;
    const int c = tid & 31, r0 = tid >> 5;
    #pragma unroll
    for (int i = 0; i < 4; ++i) {
        int r = r0 + i * 8;
        tile[r][c] = film_w[(size_t)(k0 + r) * 2048 + n0 + c];
    }
    __syncthreads();
    #pragma unroll
    for (int i = 0; i < 4; ++i) {
        int rn = r0 + i * 8;            // n within tile
        float f = tile[c][rn];          // film_w[k0+c][n0+rn]
        float fh;
        unsigned short hs = f2bf_hi(f, &fh);
        unsigned short ls = f2bf(f - fh);
        Bhi[(size_t)(n0 + rn) * 1408 + k0 + c] = hs;
        Blo[(size_t)(n0 + rn) * 1408 + k0 + c] = ls;
    }
}

// ---------------------------------------------------------------------------
// K1: boundary logit + key logits (49-col mini-GEMM, 32 tokens / block)
//     A reads are wave-broadcast float4 (12 LDS ops / 32 FMA, was 36).
// ---------------------------------------------------------------------------
__global__ __launch_bounds__(256) void k_logits(
    const float* __restrict__ h, const float* __restrict__ bound_w,
    const float* __restrict__ bound_b, const float* __restrict__ key_w,
    const float* __restrict__ key_b, float* __restrict__ ws)
{
    __shared__ __align__(16) float As[32][68];   // [row][k], 272B stride (16B-aligned)
    __shared__ float Ws[64][64];                 // [k][col], cols 0..47 key, 48 bound
    const int tid  = threadIdx.x;
    const int tok0 = blockIdx.x * 32;
    const int c  = tid & 63;       // output column 0..63 (49 used)
    const int rg = tid >> 6;       // wave id 0..3
    const int arow = tid >> 3;     // A-fill row 0..31
    const int akb  = (tid & 7) * 8; // A-fill k 0..56
    float acc[8] = {0,0,0,0,0,0,0,0};

    for (int kc = 0; kc < 1024; kc += 64) {
        {
            const float* src = &h[(size_t)(tok0 + arow) * 1024 + kc + akb];
            float4 a0 = *(const float4*)(src);
            float4 a1 = *(const float4*)(src + 4);
            *(float4*)&As[arow][akb]     = a0;
            *(float4*)&As[arow][akb + 4] = a1;
        }
        #pragma unroll
        for (int i = 0; i < 12; ++i) {               // 64*48 = 3072 = 256*12
            int l = tid + 256 * i;
            int r = l / 48, cc = l - r * 48;
            Ws[r][cc] = key_w[(size_t)(kc + r) * 48 + cc];
        }
        if (tid < 64) Ws[tid][48] = bound_w[kc + tid];
        __syncthreads();
        #pragma unroll
        for (int kk4 = 0; kk4 < 16; ++kk4) {
            float w0 = Ws[kk4 * 4 + 0][c];
            float w1 = Ws[kk4 * 4 + 1][c];
            float w2 = Ws[kk4 * 4 + 2][c];
            float w3 = Ws[kk4 * 4 + 3][c];
            #pragma unroll
            for (int i = 0; i < 8; ++i) {
                float4 a = *(const float4*)&As[rg * 8 + i][kk4 * 4];  // broadcast
                acc[i] += a.x * w0 + a.y * w1 + a.z * w2 + a.w * w3;
            }
        }
        __syncthreads();
    }

    if (c < 48) {
        float kb = key_b[c];
        #pragma unroll
        for (int i = 0; i < 8; ++i)
            ws[OFS_KEY + (size_t)(tok0 + rg * 8 + i) * 48 + c] = acc[i] + kb;
    } else if (c == 48) {
        float bb = bound_b[0];
        #pragma unroll
        for (int i = 0; i < 8; ++i)
            ws[OFS_BOUND + tok0 + rg * 8 + i] = acc[i] + bb;
    }
}

// ---------------------------------------------------------------------------
// K2: 9-tap conv (zero pad) + sigmoid -> b_soft
// ---------------------------------------------------------------------------
__global__ __launch_bounds__(256) void k_conv(
    const float* __restrict__ conv_w, const float* __restrict__ conv_b,
    float* __restrict__ ws)
{
    int id = blockIdx.x * 256 + threadIdx.x;
    if (id >= NT_) return;
    int b = id >> 11, t = id & 2047;
    float s = conv_b[0];
    #pragma unroll
    for (int i = 0; i < 9; ++i) {
        int tt = t + i - 4;
        if (tt >= 0 && tt < T_) s += ws[OFS_BOUND + b * T_ + tt] * conv_w[i];
    }
    ws[OFS_BSOFT + id] = 1.0f / (1.0f + expf(-s));
}

// ---------------------------------------------------------------------------
// K3: softmax over 48 keys, then p @ key_emb -> ek (128)
// ---------------------------------------------------------------------------
__global__ __launch_bounds__(128) void k_softek(
    const float* __restrict__ key_emb, float* __restrict__ ws)
{
    __shared__ float p[48];
    const int tok = blockIdx.x;
    const int tid = threadIdx.x;
    if (tid < 64) {
        float v = (tid < 48) ? ws[OFS_KEY + (size_t)tok * 48 + tid] : -1e30f;
        float m = v;
        #pragma unroll
        for (int off = 32; off; off >>= 1) m = fmaxf(m, __shfl_xor(m, off, 64));
        float e = (tid < 48) ? expf(v - m) : 0.0f;
        float s = e;
        #pragma unroll
        for (int off = 32; off; off >>= 1) s += __shfl_xor(s, off, 64);
        if (tid < 48) p[tid] = e / s;
    }
    __syncthreads();
    float acc = 0.0f;
    #pragma unroll 8
    for (int k = 0; k < 48; ++k) acc += p[k] * key_emb[k * 128 + tid];
    ws[OFS_EK + (size_t)tok * 128 + tid] = acc;
}

// ---------------------------------------------------------------------------
// K4: film_in = LN([h, eb, ek]) -> split bf16 (A_hi, A_lo); h-row LN stats
// ---------------------------------------------------------------------------
__global__ __launch_bounds__(256) void k_filmin(
    const float* __restrict__ h, const float* __restrict__ e0,
    const float* __restrict__ e1, const float* __restrict__ ln_in_g,
    const float* __restrict__ ln_in_b, float* __restrict__ ws,
    unsigned short* __restrict__ Ahi, unsigned short* __restrict__ Alo)
{
    const int tok = blockIdx.x;
    const int tid = threadIdx.x;
    const float bs = ws[OFS_BSOFT + tok];
    float val[6];
    float s_all = 0.f, ss_all = 0.f, s_h = 0.f, ss_h = 0.f;
    int n = 0;
    for (int j = tid; j < DIN_; j += 256, ++n) {
        float v;
        if (j < 1024)       v = h[(size_t)tok * 1024 + j];
        else if (j < 1280)  { int i = j - 1024; v = bs * e1[i] + (1.0f - bs) * e0[i]; }
        else                v = ws[OFS_EK + (size_t)tok * 128 + (j - 1280)];
        val[n] = v;
        s_all += v; ss_all += v * v;
        if (j < 1024) { s_h += v; ss_h += v * v; }
    }
    #pragma unroll
    for (int off = 32; off; off >>= 1) {
        s_all  += __shfl_down(s_all, off);
        ss_all += __shfl_down(ss_all, off);
        s_h    += __shfl_down(s_h, off);
        ss_h   += __shfl_down(ss_h, off);
    }
    __shared__ float red[4][4];
    const int wid = tid >> 6;
    if ((tid & 63) == 0) {
        red[wid][0] = s_all; red[wid][1] = ss_all;
        red[wid][2] = s_h;   red[wid][3] = ss_h;
    }
    __syncthreads();
    float S   = red[0][0] + red[1][0] + red[2][0] + red[3][0];
    float SS  = red[0][1] + red[1][1] + red[2][1] + red[3][1];
    float Sh  = red[0][2] + red[1][2] + red[2][2] + red[3][2];
    float SSh = red[0][3] + red[1][3] + red[2][3] + red[3][3];
    float mean  = S * (1.0f / 1408.0f);
    float var   = SS * (1.0f / 1408.0f) - mean * mean;
    float rstd  = rsqrtf(var + 1e-5f);
    float mean_h = Sh * (1.0f / 1024.0f);
    float var_h  = SSh * (1.0f / 1024.0f) - mean_h * mean_h;
    float rstd_h = rsqrtf(var_h + 1e-5f);
    if (tid == 0) {
        ws[OFS_HSTAT + tok * 2]     = mean_h;
        ws[OFS_HSTAT + tok * 2 + 1] = rstd_h;
    }
    n = 0;
    for (int j = tid; j < DIN_; j += 256, ++n) {
        float f = (val[n] - mean) * rstd * ln_in_g[j] + ln_in_b[j];
        float fh;
        unsigned short hs = f2bf_hi(f, &fh);
        Ahi[(size_t)tok * 1408 + j] = hs;
        Alo[(size_t)tok * 1408 + j] = f2bf(f - fh);
    }
}

// ---------------------------------------------------------------------------
// K5: split-bf16 MFMA GEMM, FUSED single K-pass, two phases per 64-K chunk.
//     phase A: stage {Ahi, Alo, Bg_hi, Bb_hi} -> 4 hi-B combos (A_hi frags kept
//     in registers). phase B: restage only {Bg_lo, Bb_lo} -> A_hi x B_lo combos.
//     Staging 96->64 KB/chunk, barriers 132->88, MFMA:ds_read 2.0->3.0.
//     LDS 48KB resident -> 3 blocks/CU. Fused FiLM epilogue -> out slot 0.
// ---------------------------------------------------------------------------
__global__ __launch_bounds__(256) void k_gemm_mfma(
    const unsigned short* __restrict__ Ahi, const unsigned short* __restrict__ Alo,
    const unsigned short* __restrict__ Bhi, const unsigned short* __restrict__ Blo,
    const float* __restrict__ film_b, const float* __restrict__ h,
    const float* __restrict__ hstat, const float* __restrict__ ln_h_g,
    const float* __restrict__ ln_h_b, float* __restrict__ out)
{
    // LDS: Ahi [128][64]bf16 @0 (16K), Alo @16384, Bg [64][64] @32768, Bb @40960
    __shared__ __align__(16) char lds[49152];
    const int tid  = threadIdx.x;
    const int m0   = blockIdx.x * 128;
    const int n0   = blockIdx.y * 64;
    const int lane = tid & 63;
    const int wid  = tid >> 6;
    const int wm   = wid >> 1, wn = wid & 1;      // wave grid 2x2
    const int lr   = lane & 15;
    const int hi16 = ((lane >> 4) & 3) * 16;      // byte offset of 8-elem k-chunk
    const int sa   = (lr & 7) << 4;               // read-side XOR swizzle
    // staging: thread t stages 16B; LDS linear dest, source k pre-swizzled
    const int srow = tid >> 3;                    // 0..31 (+c*32)
    const int sswz = ((((tid & 7) * 16) ^ ((srow & 7) << 4)) >> 1); // ushort off
    const int sdst = tid * 16;

    f32x4 accg[4][2] = {};
    f32x4 accb[4][2] = {};

    for (int kc = 0; kc < 1408; kc += 64) {
        // ---- phase A staging: Ahi, Alo, Bg_hi, Bb_hi (12 x 16B / thread)
        #pragma unroll
        for (int c = 0; c < 4; ++c) {
            gload_lds16(Ahi + (size_t)(m0 + srow + c * 32) * 1408 + kc + sswz,
                        lds + c * 4096 + sdst);
            gload_lds16(Alo + (size_t)(m0 + srow + c * 32) * 1408 + kc + sswz,
                        lds + 16384 + c * 4096 + sdst);
        }
        #pragma unroll
        for (int c = 0; c < 2; ++c) {
            gload_lds16(Bhi + (size_t)(n0 + srow + c * 32) * 1408 + kc + sswz,
                        lds + 32768 + c * 4096 + sdst);
            gload_lds16(Bhi + (size_t)(1024 + n0 + srow + c * 32) * 1408 + kc + sswz,
                        lds + 40960 + c * 4096 + sdst);
        }
        __syncthreads();   // drains vmcnt(0): phase-A tiles visible

        s16x8 afK[2][4];   // A_hi fragments, kept for phase B (static idx)
        #pragma unroll
        for (int ks = 0; ks < 2; ++ks) {
            s16x8 al[4], bg[2], bb[2];
            #pragma unroll
            for (int mt = 0; mt < 4; ++mt) {
                int row = wm * 64 + mt * 16 + lr;
                int koff = (ks * 64 + hi16) ^ sa;
                afK[ks][mt] = *(const s16x8*)(lds + row * 128 + koff);
                al[mt]      = *(const s16x8*)(lds + 16384 + row * 128 + koff);
            }
            #pragma unroll
            for (int nt = 0; nt < 2; ++nt) {
                int off = (wn * 32 + nt * 16 + lr) * 128 + ((ks * 64 + hi16) ^ sa);
                bg[nt] = *(const s16x8*)(lds + 32768 + off);
                bb[nt] = *(const s16x8*)(lds + 40960 + off);
            }
            #pragma unroll
            for (int mt = 0; mt < 4; ++mt)
                #pragma unroll
                for (int nt = 0; nt < 2; ++nt) {
                    accg[mt][nt] = __builtin_amdgcn_mfma_f32_16x16x32_bf16(
                        afK[ks][mt], bg[nt], accg[mt][nt], 0, 0, 0);
                    accg[mt][nt] = __builtin_amdgcn_mfma_f32_16x16x32_bf16(
                        al[mt], bg[nt], accg[mt][nt], 0, 0, 0);
                    accb[mt][nt] = __builtin_amdgcn_mfma_f32_16x16x32_bf16(
                        afK[ks][mt], bb[nt], accb[mt][nt], 0, 0, 0);
                    accb[mt][nt] = __builtin_amdgcn_mfma_f32_16x16x32_bf16(
                        al[mt], bb[nt], accb[mt][nt], 0, 0, 0);
                }
        }
        __syncthreads();   // all waves done reading Bg/Bb (hi) slots

        // ---- phase B staging: only Bg_lo, Bb_lo (4 x 16B / thread)
        #pragma unroll
        for (int c = 0; c < 2; ++c) {
            gload_lds16(Blo + (size_t)(n0 + srow + c * 32) * 1408 + kc + sswz,
                        lds + 32768 + c * 4096 + sdst);
            gload_lds16(Blo + (size_t)(1024 + n0 + srow + c * 32) * 1408 + kc + sswz,
                        lds + 40960 + c * 4096 + sdst);
        }
        __syncthreads();   // drains vmcnt(0): lo-B tiles visible

        #pragma unroll
        for (int ks = 0; ks < 2; ++ks) {
            s16x8 bg[2], bb[2];
            #pragma unroll
            for (int nt = 0; nt < 2; ++nt) {
                int off = (wn * 32 + nt * 16 + lr) * 128 + ((ks * 64 + hi16) ^ sa);
                bg[nt] = *(const s16x8*)(lds + 32768 + off);
                bb[nt] = *(const s16x8*)(lds + 40960 + off);
            }
            #pragma unroll
            for (int mt = 0; mt < 4; ++mt)
                #pragma unroll
                for (int nt = 0; nt < 2; ++nt) {
                    accg[mt][nt] = __builtin_amdgcn_mfma_f32_16x16x32_bf16(
                        afK[ks][mt], bg[nt], accg[mt][nt], 0, 0, 0);
                    accb[mt][nt] = __builtin_amdgcn_mfma_f32_16x16x32_bf16(
                        afK[ks][mt], bb[nt], accb[mt][nt], 0, 0, 0);
                }
        }
        __syncthreads();   // done reading lo-B + A tiles before next-chunk stage
    }

    // epilogue: C/D layout col=lane&15, row=(lane>>4)*4+reg
    #pragma unroll
    for (int mt = 0; mt < 4; ++mt) {
        #pragma unroll
        for (int r = 0; r < 4; ++r) {
            const int tok = m0 + wm * 64 + mt * 16 + ((lane >> 4) & 3) * 4 + r;
            const float mh = hstat[tok * 2], rh = hstat[tok * 2 + 1];
            #pragma unroll
            for (int nt = 0; nt < 2; ++nt) {
                const int nc = n0 + wn * 32 + nt * 16 + lr;
                float g  = accg[mt][nt][r] + film_b[nc];
                float bt = accb[mt][nt][r] + film_b[1024 + nc];
                float hv = h[(size_t)tok * 1024 + nc];
                float lnh = (hv - mh) * rh * ln_h_g[nc] + ln_h_b[nc];
                out[(size_t)tok * (18 * 1024) + nc] = lnh * (1.0f + g) + bt;
            }
        }
    }
}

// ---------------------------------------------------------------------------
// K6: window copy, slots 1..17. One block per token, 17 float4 per thread.
// ---------------------------------------------------------------------------
__global__ __launch_bounds__(256) void k_window(
    const float* __restrict__ h, float* __restrict__ out)
{
    const int tokg = blockIdx.x;
    const int t = tokg & 2047, b = tokg >> 11;
    float4* dst = (float4*)&out[(size_t)tokg * 18 * 1024];
    #pragma unroll 4
    for (int slot = 0; slot < 17; ++slot) {
        int st = t + slot - RAD_;
        st = st < 0 ? 0 : (st > T_ - 1 ? T_ - 1 : st);
        const float4* src = (const float4*)&h[(size_t)(b * T_ + st) * 1024];
        dst[(1 + slot) * 256 + threadIdx.x] = src[threadIdx.x];
    }
}

// ---------------------------------------------------------------------------
extern "C" void kernel_launch(void* const* d_in, const int* in_sizes, int n_in,
                              void* d_out, int out_size, void* d_ws, size_t ws_size,
                              hipStream_t stream)
{
    const float* h       = (const float*)d_in[0];
    const float* bound_w = (const float*)d_in[1];
    const float* bound_b = (const float*)d_in[2];
    const float* conv_w  = (const float*)d_in[3];
    const float* conv_b  = (const float*)d_in[4];
    const float* e0      = (const float*)d_in[5];
    const float* e1      = (const float*)d_in[6];
    const float* key_emb = (const float*)d_in[7];
    const float* key_w   = (const float*)d_in[8];
    const float* key_b   = (const float*)d_in[9];
    const float* ln_in_g = (const float*)d_in[10];
    const float* ln_in_b = (const float*)d_in[11];
    const float* film_w  = (const float*)d_in[12];
    const float* film_b  = (const float*)d_in[13];
    const float* ln_h_g  = (const float*)d_in[14];
    const float* ln_h_b  = (const float*)d_in[15];
    float* ws  = (float*)d_ws;
    float* out = (float*)d_out;
    unsigned short* ub  = (unsigned short*)(ws + OFS_BF16);
    unsigned short* Ahi = ub + UOFS_AHI;
    unsigned short* Alo = ub + UOFS_ALO;
    unsigned short* Bhi = ub + UOFS_BHI;
    unsigned short* Blo = ub + UOFS_BLO;

    hipLaunchKernelGGL(k_prepw, dim3(64, 44), dim3(256), 0, stream,
                       film_w, Bhi, Blo);
    hipLaunchKernelGGL(k_logits, dim3(NT_ / 32), dim3(256), 0, stream,
                       h, bound_w, bound_b, key_w, key_b, ws);
    hipLaunchKernelGGL(k_conv, dim3(NT_ / 256), dim3(256), 0, stream,
                       conv_w, conv_b, ws);
    hipLaunchKernelGGL(k_softek, dim3(NT_), dim3(128), 0, stream, key_emb, ws);
    hipLaunchKernelGGL(k_filmin, dim3(NT_), dim3(256), 0, stream,
                       h, e0, e1, ln_in_g, ln_in_b, ws, Ahi, Alo);
    hipLaunchKernelGGL(k_gemm_mfma, dim3(64, 16), dim3(256), 0, stream,
                       Ahi, Alo, Bhi, Blo, film_b, h, ws + OFS_HSTAT,
                       ln_h_g, ln_h_b, out);
    hipLaunchKernelGGL(k_window, dim3(NT_), dim3(256), 0, stream, h, out);
}